// Round 9
// baseline (111.025 us; speedup 1.0000x reference)
//
#include <hip/hip_runtime.h>

#define BATCH 4
#define NPTS  8192
#define BN    (BATCH * NPTS)   // 32768
#define GRID_MAIN 1024          // 8 (b,dir) x 32 query-groups x 4 splits

typedef _Float16 f16;
typedef f16   f16x8  __attribute__((ext_vector_type(8)));
typedef float f32x16 __attribute__((ext_vector_type(16)));

// order-preserving float <-> uint for unsigned atomicMin
__device__ __forceinline__ unsigned fkey(float f) {
    unsigned u = __float_as_uint(f);
    return u ^ (unsigned)(((int)u >> 31) | 0x80000000);
}
__device__ __forceinline__ float funkey(unsigned k) {
    unsigned u = k ^ ((k & 0x80000000u) ? 0x80000000u : 0xFFFFFFFFu);
    return __uint_as_float(u);
}

// ---- pack+init: point -> f16x8 {-2x,-2y,-2z, csq_hi, csq_lo, 0,0,0} -------
// also inits keys (+inf), zero page, done-counter. grid: (BN/256, 2) x 256
__global__ void pack_kernel(const float* __restrict__ preds,
                            const float* __restrict__ gts,
                            f16x8* __restrict__ cP,
                            f16x8* __restrict__ cG,
                            unsigned* __restrict__ keys,
                            f16x8* __restrict__ zp,
                            unsigned* __restrict__ done) {
    const int i     = blockIdx.x * 256 + threadIdx.x;
    const int which = blockIdx.y;

    keys[(size_t)which * BN + i] = 0xFFFFFFFFu;   // +inf key

    if (which == 0 && i == 0) {
        f16x8 z;
#pragma unroll
        for (int j = 0; j < 8; ++j) z[j] = (f16)0.0f;
        zp[0] = z; zp[1] = z;
        *done = 0u;
    }

    const float* src = which ? gts : preds;
    f16x8* dst       = which ? cG : cP;
    float x = src[3 * i], y = src[3 * i + 1], z = src[3 * i + 2];
    f16 xh = (f16)x, yh = (f16)y, zh = (f16)z;
    float xf = (float)xh, yf = (float)yh, zf = (float)zh;
    float csq = xf * xf + yf * yf + zf * zf;
    f16 ch = (f16)csq;
    f16 cl = (f16)(csq - (float)ch);
    f16x8 v;
    v[0] = xh * (f16)(-2.0f);
    v[1] = yh * (f16)(-2.0f);
    v[2] = zh * (f16)(-2.0f);
    v[3] = ch;
    v[4] = cl;
    v[5] = (f16)0.0f; v[6] = (f16)0.0f; v[7] = (f16)0.0f;
    dst[i] = v;
}

// ---- main: A=candidates (streamed, raw pack), B=queries (fixed) -----------
// D[c,q] = csq - 2<q,c>. Lane owns query col (l&31), 16 candidate rows ->
// min = 15 in-reg v_min + 1 shfl_xor(32). Last block finalizes the sum.
// grid: 1024 x 256. Wave: 64 queries x 2048 candidates.
__global__ void __launch_bounds__(256)
chamfer_mfma_kernel(const f16x8* __restrict__ cP,
                    const f16x8* __restrict__ cG,
                    const f16x8* __restrict__ zp,
                    unsigned* __restrict__ keys,
                    unsigned* __restrict__ done,
                    float* __restrict__ out) {
    __shared__ unsigned lastf;
    __shared__ float red[4];

    const int lane   = threadIdx.x & 63;
    const int wavein = threadIdx.x >> 6;

    const int s   = blockIdx.x & 3;              // candidate split
    const int qg  = (blockIdx.x >> 2) & 31;      // query group
    const int bd  = blockIdx.x >> 7;             // b*2 + dir
    const int b   = bd >> 1;
    const int dir = bd & 1;

    const f16x8* __restrict__ Q = dir ? cG : cP;
    const f16x8* __restrict__ C = dir ? cP : cG;

    const bool act = lane < 32;
    const int  l31 = lane & 31;

    // ---- B fragments: 64 fixed queries {qx,qy,qz,1,1,0,0,0}
    const int q0 = b * NPTS + (qg * 4 + wavein) * 64;
    const f16x8* pQ0 = act ? (Q + q0 + l31)      : zp;
    const f16x8* pQ1 = act ? (Q + q0 + 32 + l31) : zp;
    f16x8 q0r = *pQ0;
    f16x8 q1r = *pQ1;
    const float qsq0 = (float)q0r[3] + (float)q0r[4];
    const float qsq1 = (float)q1r[3] + (float)q1r[4];
    const f16 nh  = (f16)(-0.5f);                // -0.5 * (-2x) = x, exact
    const f16 one = act ? (f16)1.0f : (f16)0.0f;
    f16x8 bq0, bq1;
    bq0[0] = q0r[0] * nh; bq0[1] = q0r[1] * nh; bq0[2] = q0r[2] * nh;
    bq0[3] = one; bq0[4] = one; bq0[5] = (f16)0.0f; bq0[6] = (f16)0.0f; bq0[7] = (f16)0.0f;
    bq1[0] = q1r[0] * nh; bq1[1] = q1r[1] * nh; bq1[2] = q1r[2] * nh;
    bq1[3] = one; bq1[4] = one; bq1[5] = (f16)0.0f; bq1[6] = (f16)0.0f; bq1[7] = (f16)0.0f;

    // ---- A stream: candidates, raw pack, 1-deep prefetch
    const int c0 = b * NPTS + s * 2048;
    const f16x8* pC0 = act ? (C + c0 + l31)      : zp;
    const f16x8* pC1 = act ? (C + c0 + 32 + l31) : zp;
    const int step = act ? 64 : 0;

    f32x16 m0, m1, zacc;
#pragma unroll
    for (int i = 0; i < 16; ++i) { m0[i] = 1e30f; m1[i] = 1e30f; zacc[i] = 0.0f; }

    f16x8 a0 = *pC0, a1 = *pC1;
    pC0 += step; pC1 += step;

    for (int it = 0; it < 32; ++it) {
        f16x8 a0n = *pC0, a1n = *pC1;     // last iter over-reads ~1KB into ws: safe, unused
        pC0 += step; pC1 += step;
        f32x16 d0 = __builtin_amdgcn_mfma_f32_32x32x16_f16(a0, bq0, zacc, 0, 0, 0);
        f32x16 d1 = __builtin_amdgcn_mfma_f32_32x32x16_f16(a1, bq0, zacc, 0, 0, 0);
#pragma unroll
        for (int i = 0; i < 16; ++i)
            m0[i] = fminf(m0[i], fminf(d0[i], d1[i]));   // -> v_min3_f32
        d0 = __builtin_amdgcn_mfma_f32_32x32x16_f16(a0, bq1, zacc, 0, 0, 0);
        d1 = __builtin_amdgcn_mfma_f32_32x32x16_f16(a1, bq1, zacc, 0, 0, 0);
#pragma unroll
        for (int i = 0; i < 16; ++i)
            m1[i] = fminf(m1[i], fminf(d0[i], d1[i]));
        a0 = a0n; a1 = a1n;
    }

    // ---- in-register min over 16 candidate rows, + cross-half swap
#pragma unroll
    for (int off = 8; off >= 1; off >>= 1) {
#pragma unroll
        for (int r = 0; r < off; ++r) {
            m0[r] = fminf(m0[r], m0[r + off]);
            m1[r] = fminf(m1[r], m1[r + off]);
        }
    }
    float v0 = fminf(m0[0], __shfl_xor(m0[0], 32, 64)) + qsq0;
    float v1 = fminf(m1[0], __shfl_xor(m1[0], 32, 64)) + qsq1;

    if (act) {
        unsigned* __restrict__ kout = keys + (size_t)dir * BN;
        atomicMin(&kout[q0 + l31],      fkey(v0));
        atomicMin(&kout[q0 + 32 + l31], fkey(v1));
    }

    // ---- last-block finalize
    __threadfence();
    __syncthreads();
    if (threadIdx.x == 0) {
        unsigned prev = atomicAdd(done, 1u);
        lastf = (prev == GRID_MAIN - 1) ? 1u : 0u;
    }
    __syncthreads();
    if (lastf) {
        __threadfence();                       // acquire: see all blocks' mins
        float s0 = 0.f, s1 = 0.f, s2 = 0.f, s3 = 0.f;
        const uint4* __restrict__ k4 = (const uint4*)keys;   // 16384 entries
        for (int i = threadIdx.x; i < 2 * BN / 4; i += 256) {
            uint4 kk = k4[i];
            s0 += funkey(kk.x); s1 += funkey(kk.y);
            s2 += funkey(kk.z); s3 += funkey(kk.w);
        }
        float val = (s0 + s1) + (s2 + s3);
#pragma unroll
        for (int off = 32; off > 0; off >>= 1)
            val += __shfl_down(val, off, 64);
        if (lane == 0) red[wavein] = val;
        __syncthreads();
        if (threadIdx.x == 0)
            out[0] = red[0] + red[1] + red[2] + red[3];
    }
}

extern "C" void kernel_launch(void* const* d_in, const int* in_sizes, int n_in,
                              void* d_out, int out_size, void* d_ws, size_t ws_size,
                              hipStream_t stream) {
    const float* preds = (const float*)d_in[0];
    const float* gts   = (const float*)d_in[1];
    float* out = (float*)d_out;

    // ws: zp 0..32 | done @128 | keys @256 (256KB) | cP (512KB) | cG (512KB)
    char* ws = (char*)d_ws;
    f16x8*    zp   = (f16x8*)ws;
    unsigned* done = (unsigned*)(ws + 128);
    unsigned* keys = (unsigned*)(ws + 256);
    f16x8*    cP   = (f16x8*)(ws + 256 + (size_t)2 * BN * 4);
    f16x8*    cG   = cP + BN;

    dim3 gpack(BN / 256, 2);
    pack_kernel<<<gpack, 256, 0, stream>>>(preds, gts, cP, cG, keys, zp, done);

    chamfer_mfma_kernel<<<GRID_MAIN, 256, 0, stream>>>(cP, cG, zp, keys, done, out);
}

// Round 10
// 106.117 us; speedup vs baseline: 1.0463x; 1.0463x over previous
//
#include <hip/hip_runtime.h>

#define BATCH 4
#define NPTS  8192
#define BN    (BATCH * NPTS)   // 32768
#define GRID_MAIN 1024          // 8 (b,dir) x 32 query-groups x 4 splits

typedef _Float16 f16;
typedef f16   f16x8  __attribute__((ext_vector_type(8)));
typedef float f32x16 __attribute__((ext_vector_type(16)));

// order-preserving float <-> uint for unsigned atomicMin
__device__ __forceinline__ unsigned fkey(float f) {
    unsigned u = __float_as_uint(f);
    return u ^ (unsigned)(((int)u >> 31) | 0x80000000);
}
__device__ __forceinline__ float funkey(unsigned k) {
    unsigned u = k ^ ((k & 0x80000000u) ? 0x80000000u : 0xFFFFFFFFu);
    return __uint_as_float(u);
}

// ---- pack+init: point -> f16x8 {-2x,-2y,-2z, csq_hi, csq_lo, 0,0,0} -------
// also inits keys (+inf), zero page, done-counter. grid: (BN/256, 2) x 256
__global__ void pack_kernel(const float* __restrict__ preds,
                            const float* __restrict__ gts,
                            f16x8* __restrict__ cP,
                            f16x8* __restrict__ cG,
                            unsigned* __restrict__ keys,
                            f16x8* __restrict__ zp,
                            unsigned* __restrict__ done) {
    const int i     = blockIdx.x * 256 + threadIdx.x;
    const int which = blockIdx.y;

    keys[(size_t)which * BN + i] = 0xFFFFFFFFu;   // +inf key

    if (which == 0 && i == 0) {
        f16x8 z;
#pragma unroll
        for (int j = 0; j < 8; ++j) z[j] = (f16)0.0f;
        zp[0] = z; zp[1] = z;
        *done = 0u;
    }

    const float* src = which ? gts : preds;
    f16x8* dst       = which ? cG : cP;
    float x = src[3 * i], y = src[3 * i + 1], z = src[3 * i + 2];
    f16 xh = (f16)x, yh = (f16)y, zh = (f16)z;
    float xf = (float)xh, yf = (float)yh, zf = (float)zh;
    float csq = xf * xf + yf * yf + zf * zf;
    f16 ch = (f16)csq;
    f16 cl = (f16)(csq - (float)ch);
    f16x8 v;
    v[0] = xh * (f16)(-2.0f);
    v[1] = yh * (f16)(-2.0f);
    v[2] = zh * (f16)(-2.0f);
    v[3] = ch;
    v[4] = cl;
    v[5] = (f16)0.0f; v[6] = (f16)0.0f; v[7] = (f16)0.0f;
    dst[i] = v;
}

// ---- main: A=candidates (streamed, raw pack), B=queries (fixed) -----------
// D[c,q] = csq - 2<q,c>. Lane owns query col (l&31), 16 candidate rows ->
// min = in-reg v_min tree + 1 shfl_xor(32). Last block finalizes the sum.
// grid: 1024 x 256. Wave: 64 queries x 2048 candidates.
// __launch_bounds__(256,4): cap 128 regs/wave -- without it the compiler
// spills the f32x16 state into a ~256-reg AGPR footprint (R9: occ 23%, 105us).
__global__ void __launch_bounds__(256, 4)
chamfer_mfma_kernel(const f16x8* __restrict__ cP,
                    const f16x8* __restrict__ cG,
                    const f16x8* __restrict__ zp,
                    unsigned* __restrict__ keys,
                    unsigned* __restrict__ done,
                    float* __restrict__ out) {
    __shared__ unsigned lastf;
    __shared__ float red[4];

    const int lane   = threadIdx.x & 63;
    const int wavein = threadIdx.x >> 6;

    const int s   = blockIdx.x & 3;              // candidate split
    const int qg  = (blockIdx.x >> 2) & 31;      // query group
    const int bd  = blockIdx.x >> 7;             // b*2 + dir
    const int b   = bd >> 1;
    const int dir = bd & 1;

    const f16x8* __restrict__ Q = dir ? cG : cP;
    const f16x8* __restrict__ C = dir ? cP : cG;

    const bool act = lane < 32;
    const int  l31 = lane & 31;

    // ---- B fragments: 64 fixed queries {qx,qy,qz,1,1,0,0,0}
    const int q0 = b * NPTS + (qg * 4 + wavein) * 64;
    const f16x8* pQ0 = act ? (Q + q0 + l31)      : zp;
    const f16x8* pQ1 = act ? (Q + q0 + 32 + l31) : zp;
    f16x8 q0r = *pQ0;
    f16x8 q1r = *pQ1;
    const float qsq0 = (float)q0r[3] + (float)q0r[4];
    const float qsq1 = (float)q1r[3] + (float)q1r[4];
    const f16 nh  = (f16)(-0.5f);                // -0.5 * (-2x) = x, exact
    const f16 one = act ? (f16)1.0f : (f16)0.0f;
    f16x8 bq0, bq1;
    bq0[0] = q0r[0] * nh; bq0[1] = q0r[1] * nh; bq0[2] = q0r[2] * nh;
    bq0[3] = one; bq0[4] = one; bq0[5] = (f16)0.0f; bq0[6] = (f16)0.0f; bq0[7] = (f16)0.0f;
    bq1[0] = q1r[0] * nh; bq1[1] = q1r[1] * nh; bq1[2] = q1r[2] * nh;
    bq1[3] = one; bq1[4] = one; bq1[5] = (f16)0.0f; bq1[6] = (f16)0.0f; bq1[7] = (f16)0.0f;

    // ---- A stream: candidates, raw pack (no manual prefetch: compiler
    // schedules the loads; manual 1-deep cost +16 regs in R9)
    const f16x8* pC0;
    const f16x8* pC1;
    {
        const int c0 = b * NPTS + s * 2048;
        pC0 = act ? (C + c0 + l31)      : zp;
        pC1 = act ? (C + c0 + 32 + l31) : zp;
    }
    const int step = act ? 64 : 0;

    f32x16 m0, m1, zacc;
#pragma unroll
    for (int i = 0; i < 16; ++i) { m0[i] = 1e30f; m1[i] = 1e30f; zacc[i] = 0.0f; }

    for (int it = 0; it < 32; ++it) {
        f16x8 a0 = *pC0;
        f16x8 a1 = *pC1;
        pC0 += step; pC1 += step;
        // D = csq - 2<q,c> (csq folded in via K-slots 3,4)
        f32x16 d0 = __builtin_amdgcn_mfma_f32_32x32x16_f16(a0, bq0, zacc, 0, 0, 0);
        f32x16 d1 = __builtin_amdgcn_mfma_f32_32x32x16_f16(a1, bq0, zacc, 0, 0, 0);
#pragma unroll
        for (int i = 0; i < 16; ++i)
            m0[i] = fminf(m0[i], fminf(d0[i], d1[i]));   // -> v_min3_f32
        d0 = __builtin_amdgcn_mfma_f32_32x32x16_f16(a0, bq1, zacc, 0, 0, 0);
        d1 = __builtin_amdgcn_mfma_f32_32x32x16_f16(a1, bq1, zacc, 0, 0, 0);
#pragma unroll
        for (int i = 0; i < 16; ++i)
            m1[i] = fminf(m1[i], fminf(d0[i], d1[i]));
    }

    // ---- in-register min over 16 candidate rows, + cross-half swap
#pragma unroll
    for (int off = 8; off >= 1; off >>= 1) {
#pragma unroll
        for (int r = 0; r < off; ++r) {
            m0[r] = fminf(m0[r], m0[r + off]);
            m1[r] = fminf(m1[r], m1[r + off]);
        }
    }
    float v0 = fminf(m0[0], __shfl_xor(m0[0], 32, 64)) + qsq0;
    float v1 = fminf(m1[0], __shfl_xor(m1[0], 32, 64)) + qsq1;

    if (act) {
        unsigned* __restrict__ kout = keys + (size_t)dir * BN;
        atomicMin(&kout[q0 + l31],      fkey(v0));
        atomicMin(&kout[q0 + 32 + l31], fkey(v1));
    }

    // ---- last-block finalize
    __threadfence();
    __syncthreads();
    if (threadIdx.x == 0) {
        unsigned prev = atomicAdd(done, 1u);
        lastf = (prev == GRID_MAIN - 1) ? 1u : 0u;
    }
    __syncthreads();
    if (lastf) {
        __threadfence();                       // acquire: see all blocks' mins
        float s0 = 0.f, s1 = 0.f, s2 = 0.f, s3 = 0.f;
        const uint4* __restrict__ k4 = (const uint4*)keys;   // 16384 entries
        for (int i = threadIdx.x; i < 2 * BN / 4; i += 256) {
            uint4 kk = k4[i];
            s0 += funkey(kk.x); s1 += funkey(kk.y);
            s2 += funkey(kk.z); s3 += funkey(kk.w);
        }
        float val = (s0 + s1) + (s2 + s3);
#pragma unroll
        for (int off = 32; off > 0; off >>= 1)
            val += __shfl_down(val, off, 64);
        if (lane == 0) red[wavein] = val;
        __syncthreads();
        if (threadIdx.x == 0)
            out[0] = red[0] + red[1] + red[2] + red[3];
    }
}

extern "C" void kernel_launch(void* const* d_in, const int* in_sizes, int n_in,
                              void* d_out, int out_size, void* d_ws, size_t ws_size,
                              hipStream_t stream) {
    const float* preds = (const float*)d_in[0];
    const float* gts   = (const float*)d_in[1];
    float* out = (float*)d_out;

    // ws: zp 0..32 | done @128 | keys @256 (256KB) | cP (512KB) | cG (512KB)
    char* ws = (char*)d_ws;
    f16x8*    zp   = (f16x8*)ws;
    unsigned* done = (unsigned*)(ws + 128);
    unsigned* keys = (unsigned*)(ws + 256);
    f16x8*    cP   = (f16x8*)(ws + 256 + (size_t)2 * BN * 4);
    f16x8*    cG   = cP + BN;

    dim3 gpack(BN / 256, 2);
    pack_kernel<<<gpack, 256, 0, stream>>>(preds, gts, cP, cG, keys, zp, done);

    chamfer_mfma_kernel<<<GRID_MAIN, 256, 0, stream>>>(cP, cG, zp, keys, done, out);
}

// Round 11
// 56.312 us; speedup vs baseline: 1.9716x; 1.8844x over previous
//
#include <hip/hip_runtime.h>

#define BATCH 4
#define NPTS  8192
#define BN    (BATCH * NPTS)   // 32768

typedef _Float16 f16;
typedef f16   f16x8  __attribute__((ext_vector_type(8)));
typedef float f32x16 __attribute__((ext_vector_type(16)));

// order-preserving float <-> uint for unsigned atomicMin
__device__ __forceinline__ unsigned fkey(float f) {
    unsigned u = __float_as_uint(f);
    return u ^ (unsigned)(((int)u >> 31) | 0x80000000);
}
__device__ __forceinline__ float funkey(unsigned k) {
    unsigned u = k ^ ((k & 0x80000000u) ? 0x80000000u : 0xFFFFFFFFu);
    return __uint_as_float(u);
}

// ---- pack+init: point -> f16x8 {-2x,-2y,-2z, csq_hi, csq_lo, 0,0,0} -------
// also inits keys (+inf), zero page, out. grid: (BN/256, 2) x 256
__global__ void pack_kernel(const float* __restrict__ preds,
                            const float* __restrict__ gts,
                            f16x8* __restrict__ cP,
                            f16x8* __restrict__ cG,
                            unsigned* __restrict__ keys,
                            f16x8* __restrict__ zp,
                            float* __restrict__ out) {
    const int i     = blockIdx.x * 256 + threadIdx.x;
    const int which = blockIdx.y;

    keys[(size_t)which * BN + i] = 0xFFFFFFFFu;   // +inf key

    if (which == 0 && i == 0) {
        *out = 0.0f;
        f16x8 z;
#pragma unroll
        for (int j = 0; j < 8; ++j) z[j] = (f16)0.0f;
        zp[0] = z; zp[1] = z;
    }

    const float* src = which ? gts : preds;
    f16x8* dst       = which ? cG : cP;
    float x = src[3 * i], y = src[3 * i + 1], z = src[3 * i + 2];
    f16 xh = (f16)x, yh = (f16)y, zh = (f16)z;
    float xf = (float)xh, yf = (float)yh, zf = (float)zh;
    float csq = xf * xf + yf * yf + zf * zf;
    f16 ch = (f16)csq;
    f16 cl = (f16)(csq - (float)ch);
    f16x8 v;
    v[0] = xh * (f16)(-2.0f);
    v[1] = yh * (f16)(-2.0f);
    v[2] = zh * (f16)(-2.0f);
    v[3] = ch;
    v[4] = cl;
    v[5] = (f16)0.0f; v[6] = (f16)0.0f; v[7] = (f16)0.0f;
    dst[i] = v;
}

// ---- main: A=queries (ONE 32-row fragment), B=candidates streamed ---------
// R8 skeleton, halved register live-set (1 A-frag): a0(4)+b0,b1(8)+d0,d1(32)
// +m0(16)+zacc(16)+addr ~= 94 regs -> 4 waves/SIMD (R9/R10: ~256 -> 2).
// grid: 2048 x 256. Wave: 32 queries x 2048 candidates, 64 MFMAs.
__global__ void __launch_bounds__(256, 4)
chamfer_mfma_kernel(const f16x8* __restrict__ cP,
                    const f16x8* __restrict__ cG,
                    const f16x8* __restrict__ zp,
                    unsigned* __restrict__ keys) {
    const int lane   = threadIdx.x & 63;
    const int wavein = threadIdx.x >> 6;

    const int s   = blockIdx.x & 3;              // candidate split 0..3
    const int qg  = (blockIdx.x >> 2) & 63;      // query group 0..63
    const int bd  = blockIdx.x >> 8;             // b*2 + dir, 0..7
    const int b   = bd >> 1;
    const int dir = bd & 1;

    const f16x8* __restrict__ Q = dir ? cG : cP;
    const f16x8* __restrict__ C = dir ? cP : cG;

    const bool act = lane < 32;
    const int  l31 = lane & 31;

    // ---- A fragment: one 32-query tile {qx,qy,qz,1,1,0,0,0}
    const int q0 = b * NPTS + (qg * 4 + wavein) * 32;
    const f16x8* pA = act ? (Q + q0 + l31) : zp;
    f16x8 a0r = *pA;
    const f16 nh  = (f16)(-0.5f);                // -0.5 * (-2x) = x, exact
    const f16 one = act ? (f16)1.0f : (f16)0.0f;
    f16x8 a0;
    a0[0] = a0r[0] * nh; a0[1] = a0r[1] * nh; a0[2] = a0r[2] * nh;
    a0[3] = one; a0[4] = one;
    a0[5] = (f16)0.0f; a0[6] = (f16)0.0f; a0[7] = (f16)0.0f;

    // ---- candidate stream (lanes >=32 pinned to zero page)
    const int c0 = b * NPTS + s * 2048;
    const f16x8* pB0 = act ? (C + c0 + l31)      : zp;
    const f16x8* pB1 = act ? (C + c0 + 32 + l31) : zp;
    const int step = act ? 64 : 0;

    f32x16 m0, zacc;
#pragma unroll
    for (int i = 0; i < 16; ++i) { m0[i] = 1e30f; zacc[i] = 0.0f; }

    for (int it = 0; it < 32; ++it) {            // 32 iters x 64 candidates
        f16x8 b0 = *pB0;
        f16x8 b1 = *pB1;
        pB0 += step; pB1 += step;
        // D[q,c] = csq - 2<q,c> (csq folded in via K-slots 3,4)
        f32x16 d0 = __builtin_amdgcn_mfma_f32_32x32x16_f16(a0, b0, zacc, 0, 0, 0);
        f32x16 d1 = __builtin_amdgcn_mfma_f32_32x32x16_f16(a0, b1, zacc, 0, 0, 0);
#pragma unroll
        for (int i = 0; i < 16; ++i)
            m0[i] = fminf(m0[i], fminf(d0[i], d1[i]));   // -> v_min3_f32
    }

    // ---- cross-lane min over the 32 candidate columns of each half
#pragma unroll
    for (int i = 0; i < 16; ++i) {
        float v = m0[i];
#pragma unroll
        for (int mask = 1; mask <= 16; mask <<= 1)
            v = fminf(v, __shfl_xor(v, mask, 64));
        m0[i] = v;
    }

    // ---- merge: lanes 0 and 32 own row-halves (row = (r&3)+8*(r>>2)+4*(lane>>5))
    if ((lane & 31) == 0) {
        unsigned* __restrict__ kout = keys + (size_t)dir * BN;
        const int rbase = q0 + ((lane >> 5) << 2);
#pragma unroll
        for (int r = 0; r < 16; ++r) {
            const int row = (r & 3) + 8 * (r >> 2);
            atomicMin(&kout[rbase + row], fkey(m0[r]));
        }
    }
}

// ---- finalize: decode key, + qsq (from quantized pack), global sum --------
// grid: 2*BN/256 = 256 blocks
__global__ void __launch_bounds__(256)
finalize_kernel(const unsigned* __restrict__ keys,
                const f16x8* __restrict__ cP,
                const f16x8* __restrict__ cG,
                float* __restrict__ out) {
    __shared__ float red[4];
    const int idx = blockIdx.x * 256 + threadIdx.x;   // [0, 2*BN)
    const int dir = idx >> 15;
    const int q   = idx & (BN - 1);

    f16x8 v = (dir ? cG : cP)[q];                 // query's own pack
    const float qsq = (float)v[3] + (float)v[4];  // csq_hi + csq_lo
    float val = funkey(keys[idx]) + qsq;

#pragma unroll
    for (int off = 32; off > 0; off >>= 1)
        val += __shfl_down(val, off, 64);

    const int wave = threadIdx.x >> 6;
    const int lane = threadIdx.x & 63;
    if (lane == 0) red[wave] = val;
    __syncthreads();
    if (threadIdx.x == 0)
        atomicAdd(out, red[0] + red[1] + red[2] + red[3]);
}

extern "C" void kernel_launch(void* const* d_in, const int* in_sizes, int n_in,
                              void* d_out, int out_size, void* d_ws, size_t ws_size,
                              hipStream_t stream) {
    const float* preds = (const float*)d_in[0];
    const float* gts   = (const float*)d_in[1];
    float* out = (float*)d_out;

    // ws layout: zeropage 256B | keys 256KB | cPackP 512KB | cPackG 512KB
    char* ws = (char*)d_ws;
    f16x8*    zp   = (f16x8*)ws;
    unsigned* keys = (unsigned*)(ws + 256);
    f16x8*    cP   = (f16x8*)(ws + 256 + (size_t)2 * BN * 4);
    f16x8*    cG   = cP + BN;

    dim3 gpack(BN / 256, 2);
    pack_kernel<<<gpack, 256, 0, stream>>>(preds, gts, cP, cG, keys, zp, out);

    chamfer_mfma_kernel<<<2048, 256, 0, stream>>>(cP, cG, zp, keys);

    finalize_kernel<<<2 * BN / 256, 256, 0, stream>>>(keys, cP, cG, out);
}